// Round 1
// baseline (1555.148 us; speedup 1.0000x reference)
//
#include <hip/hip_runtime.h>
#include <math.h>

// DomainTransformFilter on [8,3,1024,1024] f32.
// 3 iterations of {61-tap horizontal Gaussian, 61-tap vertical Gaussian},
// replicate padding, sigma = 10/20/40 (all ks=61). Edge-weight multiplies
// s = w/(w+1e-8) differ from 1.0 by <7.4e-8 and are dropped (validated in a
// previous round: absmax 3.9e-3 from fp32 ordering only, threshold ~1.1e-2).
//
// This version is LDS-free: the previous LDS-staged kernels sat at 33%
// VALUBusy / 30% HBM (latency-bound on barrier-phased ds_read_b32 chains).
// Each thread now keeps a register sliding window fed directly from global:
// a wave's window working set (~24 KB) fits the 32 KB L1, so the cache does
// what LDS was doing, with no barriers, no lgkmcnt stalls, and no LDS
// occupancy cap (0 LDS -> 8 waves/SIMD).

#define HH 1024
#define WW 1024
#define BB 8
#define CC 3
#define KS 61
#define HK 30

struct GW { float w[KS]; };   // by value -> kernarg -> SGPR-resident weights

// ---------------------------------------------------------------------------
// Horizontal conv. Thread = 32 consecutive outputs of one row.
// Window [X-32, X+64) = 24 aligned float4 loads (3 floats/output, L1-served).
// Block 256 thr = 8 rows x 32 segments. Replicate pad via per-component
// clamp branch, taken only by edge segments (k<8 for seg 0, k>15 for seg 31).
// ---------------------------------------------------------------------------
__global__ __launch_bounds__(256) void hconv(const float* __restrict__ in,
                                             float* __restrict__ out, GW g) {
    const int tid = threadIdx.x;
    const int seg = tid & 31;              // x-segment within row
    const int row = tid >> 5;              // 0..7
    const int y   = blockIdx.x * 8 + row;
    const int bc  = blockIdx.z;            // b*3+c

    const float* __restrict__ srow = in + ((size_t)bc * HH + y) * WW;
    const int X  = seg * 32;               // first output x
    const int xw = X - 32;                 // window start (float4-aligned)

    float acc[32];
    #pragma unroll
    for (int i = 0; i < 32; ++i) acc[i] = 0.f;

    #pragma unroll
    for (int k = 0; k < 24; ++k) {
        const int gx = xw + 4 * k;
        float4 v;
        if (gx >= 0 && gx <= WW - 4) {
            v = *(const float4*)(srow + gx);
        } else {                           // replicate pad (edge segs only)
            const int a0 = min(max(gx    , 0), WW - 1);
            const int a1 = min(max(gx + 1, 0), WW - 1);
            const int a2 = min(max(gx + 2, 0), WW - 1);
            const int a3 = min(max(gx + 3, 0), WW - 1);
            v = make_float4(srow[a0], srow[a1], srow[a2], srow[a3]);
        }
        const float vv[4] = { v.x, v.y, v.z, v.w };
        #pragma unroll
        for (int c = 0; c < 4; ++c) {
            const int j = 4 * k + c;       // window position; x_in = xw + j
            #pragma unroll
            for (int i = 0; i < 32; ++i) {
                const int t = j - 2 - i;   // tap index: x_in = X+i-30+t
                if (t >= 0 && t < KS)
                    acc[i] = fmaf(g.w[t], vv[c], acc[i]);
            }
        }
    }

    float* drow = out + ((size_t)bc * HH + y) * WW + X;
    #pragma unroll
    for (int i = 0; i < 8; ++i)
        *(float4*)(drow + 4 * i) =
            make_float4(acc[4*i], acc[4*i+1], acc[4*i+2], acc[4*i+3]);
}

// ---------------------------------------------------------------------------
// Vertical conv. Thread = 32 consecutive outputs of one column.
// Lanes span x -> every row-load is a fully coalesced 256 B wave load.
// Window = 92 rows; y-clamp is wave-uniform (SALU). Block 256 thr = 256 cols.
// ---------------------------------------------------------------------------
__global__ __launch_bounds__(256) void vconv(const float* __restrict__ in,
                                             float* __restrict__ out, GW g) {
    const int x  = blockIdx.x * 256 + threadIdx.x;
    const int Y  = blockIdx.y * 32;        // first output y
    const int bc = blockIdx.z;

    const float* __restrict__ src = in + (size_t)bc * (HH * (size_t)WW);

    float acc[32];
    #pragma unroll
    for (int i = 0; i < 32; ++i) acc[i] = 0.f;

    #pragma unroll
    for (int j = 0; j < 32 + KS - 1; ++j) {      // 0..91
        int gy = Y - HK + j;
        gy = min(max(gy, 0), HH - 1);            // replicate pad, wave-uniform
        const float v = src[(size_t)gy * WW + x];
        #pragma unroll
        for (int i = 0; i < 32; ++i) {
            const int t = j - i;
            if (t >= 0 && t < KS)
                acc[i] = fmaf(g.w[t], v, acc[i]);
        }
    }

    float* dst = out + (size_t)bc * (HH * (size_t)WW) + (size_t)Y * WW + x;
    #pragma unroll
    for (int i = 0; i < 32; ++i) dst[(size_t)i * WW] = acc[i];
}

// ---------------------------------------------------------------------------
static void fill_w(double sigma, GW* g) {
    double tmp[KS], s = 0.0;
    for (int k = 0; k < KS; ++k) {
        const double d = (double)(k - HK);
        tmp[k] = exp(-(d * d) / (2.0 * sigma * sigma));
        s += tmp[k];
    }
    for (int k = 0; k < KS; ++k) g->w[k] = (float)(tmp[k] / s);
}

extern "C" void kernel_launch(void* const* d_in, const int* in_sizes, int n_in,
                              void* d_out, int out_size, void* d_ws, size_t ws_size,
                              hipStream_t stream) {
    const float* input = (const float*)d_in[0];
    float* out = (float*)d_out;
    float* tmp = (float*)d_ws;                     // 96 MiB scratch

    GW g10, g20, g40;
    fill_w(10.0, &g10);
    fill_w(20.0, &g20);
    fill_w(40.0, &g40);

    const dim3 hb(256), hg(HH / 8, 1, BB * CC);        // 128 x 1 x 24
    const dim3 vb(256), vg(WW / 256, HH / 32, BB * CC); // 4 x 32 x 24

    hconv<<<hg, hb, 0, stream>>>(input, tmp, g10);
    vconv<<<vg, vb, 0, stream>>>(tmp, out, g10);
    hconv<<<hg, hb, 0, stream>>>(out, tmp, g20);
    vconv<<<vg, vb, 0, stream>>>(tmp, out, g20);
    hconv<<<hg, hb, 0, stream>>>(out, tmp, g40);
    vconv<<<vg, vb, 0, stream>>>(tmp, out, g40);
}

// Round 2
// 497.650 us; speedup vs baseline: 3.1250x; 3.1250x over previous
//
#include <hip/hip_runtime.h>
#include <math.h>

// DomainTransformFilter on [8,3,1024,1024] f32.
// 3 iterations of {61-tap horizontal Gaussian, 61-tap vertical Gaussian},
// replicate padding, sigma = 10/20/40 (all ks=61). Edge-weight multiplies
// s = w/(w+1e-8) differ from 1.0 by <7.4e-8 and are dropped (validated:
// absmax 3.9e-3 from fp32 ordering only, threshold ~1.1e-2).
//
// Round-2 structure:
//  - hconv: per-block 8-chunk pipeline with double-buffered transposed LDS.
//    Compute of chunk k overlaps ds_write of chunk k+1 (whose global loads
//    were issued an iteration earlier -> HBM latency hidden under 976 FMAs).
//    One barrier per chunk. Kills the stage/compute convoy that held the
//    one-shot version at 33% VALUBusy.
//  - vconv: LDS-free, 16 outputs/thread (the proven compile shape: full
//    unroll, kernarg weights stay SGPR-resident, ~40 VGPR -> 8 waves/SIMD).
//    Lanes span x so every load is a coalesced 256 B wave read; halo
//    re-reads are served by L1/L2 via an XCD-chunked grid decode.

#define HH 1024
#define WW 1024
#define BB 8
#define CC 3
#define KS 61
#define HK 30

struct GW { float w[KS]; };   // by value -> kernarg -> SGPR-resident weights

// ---------------------------------------------------------------------------
// Horizontal conv, pipelined. Block 256 thr, strip = 32 rows x 1024 cols,
// 8 chunks of 128 out-cols. LDS ring[2][192][33]: transposed window
// (col-major, stride 33 -> compute reads are 2-way/bank = free; staging
// writes 2-way = free). 50.7 KB -> 3 blocks/CU.
// ---------------------------------------------------------------------------
__global__ __launch_bounds__(256) void hconv(const float* __restrict__ in,
                                             float* __restrict__ out, GW g) {
    __shared__ float ring[2][192][33];
    const int strip = blockIdx.x;          // 0..31 (32-row strips)
    const int bc    = blockIdx.y;          // 0..23
    const int t     = threadIdx.x;

    const float* __restrict__ src = in + ((size_t)bc * HH + strip * 32) * WW;

    const int sr = t >> 3;                 // staging row   0..31
    const int sq = t & 7;                  // staging quad  0..7
    const int y  = t & 31;                 // compute row   0..31
    const int xg = t >> 5;                 // compute x-grp 0..7

    float4 st[6];                          // staged regs for next chunk

    auto LOADW = [&](int k) {              // issue global loads, window of chunk k
        const float* rowp = src + (size_t)sr * WW;
        #pragma unroll
        for (int m = 0; m < 6; ++m) {
            const int c0 = 128 * k - 32 + 4 * (sq + 8 * m);   // window col
            if (c0 >= 0 && c0 + 3 < WW) {
                st[m] = *(const float4*)(rowp + c0);
            } else {                       // replicate pad (edge chunks only)
                const int a0 = min(max(c0    , 0), WW - 1);
                const int a1 = min(max(c0 + 1, 0), WW - 1);
                const int a2 = min(max(c0 + 2, 0), WW - 1);
                const int a3 = min(max(c0 + 3, 0), WW - 1);
                st[m] = make_float4(rowp[a0], rowp[a1], rowp[a2], rowp[a3]);
            }
        }
    };
    auto WRITEW = [&](int slot) {          // transposed ds_write of staged regs
        #pragma unroll
        for (int m = 0; m < 6; ++m) {
            const int w = 4 * (sq + 8 * m);
            ring[slot][w + 0][sr] = st[m].x;
            ring[slot][w + 1][sr] = st[m].y;
            ring[slot][w + 2][sr] = st[m].z;
            ring[slot][w + 3][sr] = st[m].w;
        }
    };

    LOADW(0); WRITEW(0); LOADW(1);
    __syncthreads();

    float* __restrict__ dstrow = out + ((size_t)bc * HH + strip * 32 + y) * WW;

    for (int k = 0; k < 8; ++k) {          // dynamic loop: no code bloat
        const int slot = k & 1;
        float acc[16];
        #pragma unroll
        for (int i = 0; i < 16; ++i) acc[i] = 0.f;

        // window col w = 16*xg + 2 + j  <->  input x = 128k + 16xg - 30 + j
        #pragma unroll
        for (int j = 0; j < 76; ++j) {
            const float v = ring[slot][16 * xg + 2 + j][y];
            #pragma unroll
            for (int i = 0; i < 16; ++i) {
                const int tt = j - i;      // tap index for output i
                if (tt >= 0 && tt < KS)
                    acc[i] = fmaf(g.w[tt], v, acc[i]);
            }
        }

        if (k < 7) {
            WRITEW(1 - slot);              // stage chunk k+1 (loads landed)
            if (k < 6) LOADW(k + 2);       // issue loads for chunk k+2
        }

        float* d = dstrow + 128 * k + 16 * xg;
        #pragma unroll
        for (int i = 0; i < 4; ++i)
            *(float4*)(d + 4 * i) = make_float4(acc[4*i], acc[4*i+1],
                                                acc[4*i+2], acc[4*i+3]);
        __syncthreads();                   // one barrier per chunk
    }
}

// ---------------------------------------------------------------------------
// Vertical conv, LDS-free. Thread = 16 consecutive outputs of one column
// (proven compile shape). Lanes span x -> coalesced 256 B wave loads;
// y-clamp is wave-uniform. XCD-chunked flat grid: 6144 = 8 * 768; each XCD
// owns 3 complete (bc,xq) column strips so vertical-halo re-reads stay in
// its private L2.
// ---------------------------------------------------------------------------
__global__ __launch_bounds__(256) void vconv(const float* __restrict__ in,
                                             float* __restrict__ out, GW g) {
    const int f   = blockIdx.x;            // 0..6143
    const int c   = f & 7;                 // XCD (dispatch round-robin)
    const int idx = f >> 3;                // 0..767
    const int w0  = c * 768 + idx;         // work id, Y-fastest
    const int Yt  = w0 & 63;
    const int r1  = w0 >> 6;
    const int xq  = r1 & 3;
    const int bc  = r1 >> 2;

    const int x = xq * 256 + threadIdx.x;
    const int Y = Yt * 16;                 // first output y

    const float* __restrict__ src = in + (size_t)bc * (HH * (size_t)WW);

    float acc[16];
    #pragma unroll
    for (int i = 0; i < 16; ++i) acc[i] = 0.f;

    #pragma unroll
    for (int j = 0; j < 76; ++j) {
        int gy = Y - HK + j;
        gy = min(max(gy, 0), HH - 1);      // replicate pad, wave-uniform
        const float v = src[(size_t)gy * WW + x];
        #pragma unroll
        for (int i = 0; i < 16; ++i) {
            const int tt = j - i;
            if (tt >= 0 && tt < KS)
                acc[i] = fmaf(g.w[tt], v, acc[i]);
        }
    }

    float* dst = out + (size_t)bc * (HH * (size_t)WW) + (size_t)Y * WW + x;
    #pragma unroll
    for (int i = 0; i < 16; ++i) dst[(size_t)i * WW] = acc[i];
}

// ---------------------------------------------------------------------------
static void fill_w(double sigma, GW* g) {
    double tmp[KS], s = 0.0;
    for (int k = 0; k < KS; ++k) {
        const double d = (double)(k - HK);
        tmp[k] = exp(-(d * d) / (2.0 * sigma * sigma));
        s += tmp[k];
    }
    for (int k = 0; k < KS; ++k) g->w[k] = (float)(tmp[k] / s);
}

extern "C" void kernel_launch(void* const* d_in, const int* in_sizes, int n_in,
                              void* d_out, int out_size, void* d_ws, size_t ws_size,
                              hipStream_t stream) {
    const float* input = (const float*)d_in[0];
    float* out = (float*)d_out;
    float* tmp = (float*)d_ws;                     // 96 MiB scratch

    GW g10, g20, g40;
    fill_w(10.0, &g10);
    fill_w(20.0, &g20);
    fill_w(40.0, &g40);

    const dim3 hb(256), hg(HH / 32, BB * CC);      // 32 x 24 strips
    const dim3 vb(256), vg(8 * 768);               // XCD-chunked flat grid

    hconv<<<hg, hb, 0, stream>>>(input, tmp, g10);
    vconv<<<vg, vb, 0, stream>>>(tmp, out, g10);
    hconv<<<hg, hb, 0, stream>>>(out, tmp, g20);
    vconv<<<vg, vb, 0, stream>>>(tmp, out, g20);
    hconv<<<hg, hb, 0, stream>>>(out, tmp, g40);
    vconv<<<vg, vb, 0, stream>>>(tmp, out, g40);
}